// Round 9
// baseline (2612.794 us; speedup 1.0000x reference)
//
#include <hip/hip_runtime.h>
#include <hip/hip_bf16.h>
#include <math.h>

// ---------------------------------------------------------------------------
// PriorEnhancedMindEncoder forward, fp32.
// Shapes: B=64, N=360, DH=256, H=8. dh(GAT0/1)=32, dh(GAT2)=256.
//
// Dead-code: adj_norm strictly positive -> GAT mask all-true -> group_prior/
// Wp1/Wp2 branch skipped.
// Fusion 1: nf = mind@(Wnp@Wrf_top) + roi@Wrf_bot + (bnp@Wrf_top+brf), LN+GELU.
// Fusion 2: GAT2 collapse: out = sum_h alpha_h @ (h2 @ G_h), G_h = gatW2_h@projW_h.
// R3: gemm 128x64 tile, 8x4 microtile, K-step 32, dbuf LDS.
// R8: row-tiled agg was 4x Z over-fetch (FETCH 390MB vs 94MB floor, 12
//     same-b blocks across XCDs). R9: COL-tiled aggregation - block = 360
//     rows x 32 cols; col slices disjoint -> V read exactly once per
//     dispatch. Scores recomputed per col-block (8x redundant exp, ~15% of
//     FMA cost); rowsum free in multiply loop (rsum += a); per-head
//     normalization folded into cross-head register acc.
// ---------------------------------------------------------------------------

#define B_ 64
#define N_ 360
#define D_ 256
#define H_ 8
#define ROWS_ (B_ * N_)   // 23040
#define CH 32             // m-chunk for scores in LDS
#define SCST 368          // scT row stride (floats)

__device__ __forceinline__ float gelu_f(float x) {
    return 0.5f * x * (1.f + erff(x * 0.70710678118654752440f));
}

// ---------------------------------------------------------------------------
// Tiled fp32 GEMM: C[M,N] = A1[M,K1]@B1[K1,N] (+ A2[M,K2]@B2[K2,N]) + bias
// 128x64 tile, 256 threads, 8x4 microtile, K-step 32, double-buffered LDS.
// z-batch: pass-0 A/B and C shifted by z*sA / z*sB / z*sC elements.
// ---------------------------------------------------------------------------
__global__ __launch_bounds__(256) void gemm_tiled(
    const float* __restrict__ A1, const float* __restrict__ B1, int K1, int lda1, int ldb1,
    const float* __restrict__ A2, const float* __restrict__ B2, int K2, int lda2, int ldb2,
    const float* __restrict__ bias, float* __restrict__ C, int M, int N, int ldc,
    size_t sA, size_t sB, size_t sC)
{
    __shared__ float As[2][32][132];
    __shared__ float Bs[2][32][64];
    const int tid = threadIdx.x;
    const int z = blockIdx.z;
    const int bm = blockIdx.y * 128;
    const int bn = blockIdx.x * 64;
    const int tr = (tid >> 4) * 8;
    const int tc = (tid & 15) * 4;
    const int lar = tid >> 3;
    const int lak = (tid & 7) * 4;
    const int lbk = tid >> 4;
    const int lbc = (tid & 15) * 4;

    float acc[8][4] = {};
    float4 rA[4], rB[2];

    for (int pass = 0; pass < 2; ++pass) {
        const float* Ab = pass ? A2 : A1;
        const float* Bb = pass ? B2 : B1;
        if (Ab == nullptr) continue;
        const float* A  = Ab + (pass ? (size_t)0 : (size_t)z * sA);
        const float* Bm = Bb + (pass ? (size_t)0 : (size_t)z * sB);
        const int K   = pass ? K2 : K1;
        const int lda = pass ? lda2 : lda1;
        const int ldb = pass ? ldb2 : ldb1;
        const int S = (K + 31) >> 5;

        auto loadA = [&](int s) {
            const int k0 = s << 5;
            #pragma unroll
            for (int j = 0; j < 4; ++j) {
                const int gr = bm + lar + j * 32;
                const int gk = k0 + lak;
                float4 v; v.x = v.y = v.z = v.w = 0.f;
                if (gr < M) {
                    if (gk + 3 < K) {
                        v = *(const float4*)&A[(size_t)gr * lda + gk];
                    } else {
                        float t0 = 0.f, t1 = 0.f, t2 = 0.f, t3 = 0.f;
                        if (gk + 0 < K) t0 = A[(size_t)gr * lda + gk + 0];
                        if (gk + 1 < K) t1 = A[(size_t)gr * lda + gk + 1];
                        if (gk + 2 < K) t2 = A[(size_t)gr * lda + gk + 2];
                        if (gk + 3 < K) t3 = A[(size_t)gr * lda + gk + 3];
                        v.x = t0; v.y = t1; v.z = t2; v.w = t3;
                    }
                }
                rA[j] = v;
            }
        };
        auto loadB = [&](int s) {
            const int k0 = s << 5;
            #pragma unroll
            for (int j = 0; j < 2; ++j) {
                const int gk = k0 + lbk + j * 16;
                float4 v; v.x = v.y = v.z = v.w = 0.f;
                if (gk < K) v = *(const float4*)&Bm[(size_t)gk * ldb + bn + lbc];
                rB[j] = v;
            }
        };
        auto storeA = [&](int buf) {
            #pragma unroll
            for (int j = 0; j < 4; ++j) {
                const int row = lar + j * 32;
                As[buf][lak + 0][row] = rA[j].x;
                As[buf][lak + 1][row] = rA[j].y;
                As[buf][lak + 2][row] = rA[j].z;
                As[buf][lak + 3][row] = rA[j].w;
            }
        };
        auto storeB = [&](int buf) {
            #pragma unroll
            for (int j = 0; j < 2; ++j)
                *(float4*)&Bs[buf][lbk + j * 16][lbc] = rB[j];
        };

        loadA(0); loadB(0);
        storeA(0); storeB(0);
        __syncthreads();
        for (int s = 0; s < S; ++s) {
            const int cur = s & 1;
            if (s + 1 < S) { loadA(s + 1); loadB(s + 1); }
            #pragma unroll
            for (int k = 0; k < 32; ++k) {
                const float4 a0 = *(const float4*)&As[cur][k][tr];
                const float4 a1 = *(const float4*)&As[cur][k][tr + 4];
                const float4 bv = *(const float4*)&Bs[cur][k][tc];
                const float av[8] = {a0.x, a0.y, a0.z, a0.w, a1.x, a1.y, a1.z, a1.w};
                const float bb[4] = {bv.x, bv.y, bv.z, bv.w};
                #pragma unroll
                for (int i = 0; i < 8; ++i)
                    #pragma unroll
                    for (int j = 0; j < 4; ++j)
                        acc[i][j] += av[i] * bb[j];
            }
            if (s + 1 < S) { storeA(cur ^ 1); storeB(cur ^ 1); }
            __syncthreads();
        }
    }

    float4 bz; bz.x = bz.y = bz.z = bz.w = 0.f;
    if (bias) bz = *(const float4*)&bias[bn + tc];
    float* Cz = C + (size_t)z * sC;
    #pragma unroll
    for (int i = 0; i < 8; ++i) {
        const int r = bm + tr + i;
        if (r < M) {
            float4 o;
            o.x = acc[i][0] + bz.x;
            o.y = acc[i][1] + bz.y;
            o.z = acc[i][2] + bz.z;
            o.w = acc[i][3] + bz.w;
            *(float4*)&Cz[(size_t)r * ldc + bn + tc] = o;
        }
    }
}

// bias_comb[c] = brf[c] + sum_k bnp[k] * Wrf[k, c]
__global__ __launch_bounds__(256) void biascomb_kernel(
    const float* __restrict__ bnp, const float* __restrict__ Wrf,
    const float* __restrict__ brf, float* __restrict__ bcomb)
{
    int c = threadIdx.x;
    float acc = brf[c];
    for (int k = 0; k < 256; ++k) acc += bnp[k] * Wrf[k * 256 + c];
    bcomb[c] = acc;
}

// u[h][i] = sum_j gatW2[i, h*256+j] * a2[h, j]; v[h][i] with a2[h, 256+j]
__global__ __launch_bounds__(256) void uv_kernel(
    const float* __restrict__ gatW2, const float* __restrict__ a2,
    float* __restrict__ u, float* __restrict__ v)
{
    const int h = blockIdx.x;
    const int i = threadIdx.x;
    const float* wrow = gatW2 + (size_t)i * 2048 + h * 256;
    const float* ai = a2 + h * 512;
    float su = 0.f, sv = 0.f;
    for (int j = 0; j < 256; ++j) {
        float w = wrow[j];
        su += w * ai[j];
        sv += w * ai[256 + j];
    }
    u[h * 256 + i] = su;
    v[h * 256 + i] = sv;
}

// LayerNorm(eps=1e-5) + exact GELU, in-place on rows of 256. 1 wave per row.
__global__ __launch_bounds__(64) void ln_gelu_kernel(
    float* __restrict__ x, const float* __restrict__ g, const float* __restrict__ b)
{
    const size_t row = blockIdx.x;
    const int t = threadIdx.x;
    float4 v = *(const float4*)&x[row * 256 + t * 4];
    float s = v.x + v.y + v.z + v.w;
    #pragma unroll
    for (int m = 1; m < 64; m <<= 1) s += __shfl_xor(s, m);
    float mean = s * (1.f / 256.f);
    float dx = v.x - mean, dy = v.y - mean, dz = v.z - mean, dw = v.w - mean;
    float q = dx * dx + dy * dy + dz * dz + dw * dw;
    #pragma unroll
    for (int m = 1; m < 64; m <<= 1) q += __shfl_xor(q, m);
    float rstd = 1.f / sqrtf(q * (1.f / 256.f) + 1e-5f);
    float4 gg = *(const float4*)&g[t * 4];
    float4 bb = *(const float4*)&b[t * 4];
    float4 r;
    r.x = gelu_f(dx * rstd * gg.x + bb.x);
    r.y = gelu_f(dy * rstd * gg.y + bb.y);
    r.z = gelu_f(dz * rstd * gg.z + bb.z);
    r.w = gelu_f(dw * rstd * gg.w + bb.w);
    *(float4*)&x[row * 256 + t * 4] = r;
}

// ei/ej for GAT0/1: per row: ei[h] = ht[row,h,:dh] . a[h,:dh]
template <int DH>
__global__ __launch_bounds__(64) void eiej_kernel(
    const float* __restrict__ ht, const float* __restrict__ a,
    float* __restrict__ ei, float* __restrict__ ej)
{
    const size_t row = blockIdx.x;
    const int t = threadIdx.x;
    constexpr int E = (H_ * DH) / 64;
    const int h = t >> 3;
    const int d0 = (t & 7) * E;
    const float* hp = ht + row * (H_ * DH) + h * DH + d0;
    const float* ap = a + h * 2 * DH + d0;
    float se = 0.f, sj = 0.f;
    #pragma unroll
    for (int i = 0; i < E; i += 4) {
        float4 x = *(const float4*)&hp[i];
        float4 u = *(const float4*)&ap[i];
        float4 w = *(const float4*)&ap[DH + i];
        se += x.x * u.x + x.y * u.y + x.z * u.z + x.w * u.w;
        sj += x.x * w.x + x.y * w.y + x.z * w.z + x.w * w.w;
    }
    se += __shfl_xor(se, 1); sj += __shfl_xor(sj, 1);
    se += __shfl_xor(se, 2); sj += __shfl_xor(sj, 2);
    se += __shfl_xor(se, 4); sj += __shfl_xor(sj, 4);
    if ((t & 7) == 0) {
        ei[row * H_ + h] = se;
        ej[row * H_ + h] = sj;
    }
}

// ei2/ej2 for GAT2: ei2[row,h] = h2[row,:] . u[h,:], ej2 with v.
__global__ __launch_bounds__(64) void eiej2_kernel(
    const float* __restrict__ h2, const float* __restrict__ u,
    const float* __restrict__ v, float* __restrict__ ei, float* __restrict__ ej)
{
    const size_t row = blockIdx.x;
    const int t = threadIdx.x;
    const int h = t >> 3;
    const int d0 = (t & 7) * 32;
    const float* hp = h2 + row * 256 + d0;
    const float* up = u + h * 256 + d0;
    const float* vp = v + h * 256 + d0;
    float se = 0.f, sj = 0.f;
    #pragma unroll
    for (int i = 0; i < 32; i += 4) {
        float4 x = *(const float4*)&hp[i];
        float4 uu = *(const float4*)&up[i];
        float4 vv = *(const float4*)&vp[i];
        se += x.x * uu.x + x.y * uu.y + x.z * uu.z + x.w * uu.w;
        sj += x.x * vv.x + x.y * vv.y + x.z * vv.z + x.w * vv.w;
    }
    se += __shfl_xor(se, 1); sj += __shfl_xor(sj, 1);
    se += __shfl_xor(se, 2); sj += __shfl_xor(sj, 2);
    se += __shfl_xor(se, 4); sj += __shfl_xor(sj, 4);
    if ((t & 7) == 0) {
        ei[row * H_ + h] = se;
        ej[row * H_ + h] = sj;
    }
}

// ---------------------------------------------------------------------------
// GAT0/1 aggregation, COL-tiled: block = (head h, batch b), 360 rows x 32
// cols (head h's slice). V (=ht cols h*32..+31) read exactly once per
// dispatch. Scores chunked 32-m in scT[32][368]; rowsum accumulated in the
// multiply loop (rsum += a); normalize in epilogue.
// Roles: score = (smm = tid>>3, srs = tid&7 -> 45 rows each);
//        mult  = (rg = tid>>2 < 60 -> 6 rows, cg = tid&3 -> 8 cols).
// ---------------------------------------------------------------------------
__global__ __launch_bounds__(256) void gat01_aggC(
    const float* __restrict__ ht, const float* __restrict__ ei,
    const float* __restrict__ ej, float* __restrict__ out)
{
    __shared__ float scT[CH][SCST];    // 47104 B
    __shared__ float ejs[N_], eis[N_], mrow_s[N_];
    __shared__ float red4[4];
    const int tid = threadIdx.x;
    const int h = blockIdx.x;
    const int b = blockIdx.y;

    for (int r = tid; r < N_; r += 256) {
        ejs[r] = ej[(size_t)(b * N_ + r) * H_ + h];
        eis[r] = ei[(size_t)(b * N_ + r) * H_ + h];
    }
    __syncthreads();
    float mx = -1e30f;
    for (int m = tid; m < N_; m += 256) mx = fmaxf(mx, ejs[m]);
    #pragma unroll
    for (int s = 1; s < 64; s <<= 1) mx = fmaxf(mx, __shfl_xor(mx, s));
    if ((tid & 63) == 0) red4[tid >> 6] = mx;
    __syncthreads();
    const float maxej = fmaxf(fmaxf(red4[0], red4[1]), fmaxf(red4[2], red4[3]));
    for (int r = tid; r < N_; r += 256) {
        float t = eis[r] + maxej;
        mrow_s[r] = t > 0.f ? t : 0.2f * t;   // lrelu monotonic -> row max
    }
    __syncthreads();

    const int smm = tid >> 3, srs = tid & 7;
    const int cg = tid & 3, rg = tid >> 2;
    const float* Vp = ht + (size_t)b * N_ * D_ + h * 32 + cg * 8;
    float acc[6][8] = {};
    float rsum[6] = {};

    for (int c0 = 0; c0 < N_; c0 += CH) {
        const int mcnt = min(CH, N_ - c0);
        if (smm < mcnt) {
            const float ejv = ejs[c0 + smm];
            float* sp = &scT[smm][srs * 45];
            const float* ep = &eis[srs * 45];
            const float* mp = &mrow_s[srs * 45];
            #pragma unroll 5
            for (int i = 0; i < 45; ++i) {
                float e = ep[i] + ejv;
                e = e > 0.f ? e : 0.2f * e;
                sp[i] = __expf(e - mp[i]);
            }
        }
        __syncthreads();
        if (rg < 60) {
            for (int mm = 0; mm < mcnt; ++mm) {
                const float2 a0 = *(const float2*)&scT[mm][rg * 6 + 0];
                const float2 a1 = *(const float2*)&scT[mm][rg * 6 + 2];
                const float2 a2 = *(const float2*)&scT[mm][rg * 6 + 4];
                const float a[6] = {a0.x, a0.y, a1.x, a1.y, a2.x, a2.y};
                const size_t mo = (size_t)(c0 + mm) * D_;
                const float4 v0 = *(const float4*)&Vp[mo];
                const float4 v1 = *(const float4*)&Vp[mo + 4];
                const float v[8] = {v0.x, v0.y, v0.z, v0.w, v1.x, v1.y, v1.z, v1.w};
                #pragma unroll
                for (int i = 0; i < 6; ++i) {
                    rsum[i] += a[i];
                    #pragma unroll
                    for (int j = 0; j < 8; ++j)
                        acc[i][j] += a[i] * v[j];
                }
            }
        }
        __syncthreads();
    }

    if (rg < 60) {
        #pragma unroll
        for (int i = 0; i < 6; ++i) {
            const int r = rg * 6 + i;
            const float ri = 1.f / rsum[i];
            float* op = out + (size_t)(b * N_ + r) * D_ + h * 32 + cg * 8;
            float4 o0, o1;
            o0.x = acc[i][0] * ri; o0.y = acc[i][1] * ri;
            o0.z = acc[i][2] * ri; o0.w = acc[i][3] * ri;
            o1.x = acc[i][4] * ri; o1.y = acc[i][5] * ri;
            o1.z = acc[i][6] * ri; o1.w = acc[i][7] * ri;
            *(float4*)&op[0] = o0;
            *(float4*)&op[4] = o1;
        }
    }
}

// ---------------------------------------------------------------------------
// GAT2 aggregation, COL-tiled, 4 heads/dispatch with cross-head register
// accumulator. Block = (colslice, b): 360 rows x 32 cols. Z_h col slices
// disjoint across blocks -> Z read exactly once per dispatch (94MB floor;
// R8 row-tiled was 390MB). Per-head acc_h folded: acc += (1/rsum)*acc_h.
// ---------------------------------------------------------------------------
__global__ __launch_bounds__(256) void gat2_aggC4(
    const float* __restrict__ Zbase, size_t zstride,
    const float* __restrict__ ei, const float* __restrict__ ej,
    const float* __restrict__ projb, float* __restrict__ out,
    int hbase, int first)
{
    __shared__ float scT[CH][SCST];
    __shared__ float ejs[N_], eis[N_], mrow_s[N_];
    __shared__ float red4[4];
    const int tid = threadIdx.x;
    const int cslice = blockIdx.x;
    const int b = blockIdx.y;
    const int smm = tid >> 3, srs = tid & 7;
    const int cg = tid & 3, rg = tid >> 2;
    float acc[6][8] = {};

    for (int hh = 0; hh < 4; ++hh) {
        const int h = hbase + hh;
        for (int r = tid; r < N_; r += 256) {
            ejs[r] = ej[(size_t)(b * N_ + r) * H_ + h];
            eis[r] = ei[(size_t)(b * N_ + r) * H_ + h];
        }
        __syncthreads();
        float mx = -1e30f;
        for (int m = tid; m < N_; m += 256) mx = fmaxf(mx, ejs[m]);
        #pragma unroll
        for (int s = 1; s < 64; s <<= 1) mx = fmaxf(mx, __shfl_xor(mx, s));
        if ((tid & 63) == 0) red4[tid >> 6] = mx;
        __syncthreads();
        const float maxej = fmaxf(fmaxf(red4[0], red4[1]), fmaxf(red4[2], red4[3]));
        for (int r = tid; r < N_; r += 256) {
            float t = eis[r] + maxej;
            mrow_s[r] = t > 0.f ? t : 0.2f * t;
        }
        __syncthreads();

        const float* Vp = Zbase + (size_t)hh * zstride
                        + (size_t)b * N_ * D_ + cslice * 32 + cg * 8;
        float acc_h[6][8] = {};
        float rsum[6] = {};

        for (int c0 = 0; c0 < N_; c0 += CH) {
            const int mcnt = min(CH, N_ - c0);
            if (smm < mcnt) {
                const float ejv = ejs[c0 + smm];
                float* sp = &scT[smm][srs * 45];
                const float* ep = &eis[srs * 45];
                const float* mp = &mrow_s[srs * 45];
                #pragma unroll 5
                for (int i = 0; i < 45; ++i) {
                    float e = ep[i] + ejv;
                    e = e > 0.f ? e : 0.2f * e;
                    sp[i] = __expf(e - mp[i]);
                }
            }
            __syncthreads();
            if (rg < 60) {
                for (int mm = 0; mm < mcnt; ++mm) {
                    const float2 a0 = *(const float2*)&scT[mm][rg * 6 + 0];
                    const float2 a1 = *(const float2*)&scT[mm][rg * 6 + 2];
                    const float2 a2 = *(const float2*)&scT[mm][rg * 6 + 4];
                    const float a[6] = {a0.x, a0.y, a1.x, a1.y, a2.x, a2.y};
                    const size_t mo = (size_t)(c0 + mm) * D_;
                    const float4 v0 = *(const float4*)&Vp[mo];
                    const float4 v1 = *(const float4*)&Vp[mo + 4];
                    const float v[8] = {v0.x, v0.y, v0.z, v0.w, v1.x, v1.y, v1.z, v1.w};
                    #pragma unroll
                    for (int i = 0; i < 6; ++i) {
                        rsum[i] += a[i];
                        #pragma unroll
                        for (int j = 0; j < 8; ++j)
                            acc_h[i][j] += a[i] * v[j];
                    }
                }
            }
            __syncthreads();
        }

        if (rg < 60) {
            #pragma unroll
            for (int i = 0; i < 6; ++i) {
                const float ri = 1.f / rsum[i];
                #pragma unroll
                for (int j = 0; j < 8; ++j)
                    acc[i][j] += acc_h[i][j] * ri;
            }
        }
        __syncthreads();   // all done with scT/ejs/eis before next head reload
    }

    if (rg < 60) {
        #pragma unroll
        for (int i = 0; i < 6; ++i) {
            const int r = rg * 6 + i;
            float* op = out + (size_t)(b * N_ + r) * D_ + cslice * 32 + cg * 8;
            if (first) {
                const float4 p0 = *(const float4*)&projb[cslice * 32 + cg * 8];
                const float4 p1 = *(const float4*)&projb[cslice * 32 + cg * 8 + 4];
                float4 o0, o1;
                o0.x = acc[i][0] + p0.x; o0.y = acc[i][1] + p0.y;
                o0.z = acc[i][2] + p0.z; o0.w = acc[i][3] + p0.w;
                o1.x = acc[i][4] + p1.x; o1.y = acc[i][5] + p1.y;
                o1.z = acc[i][6] + p1.z; o1.w = acc[i][7] + p1.w;
                *(float4*)&op[0] = o0;
                *(float4*)&op[4] = o1;
            } else {
                float4 o0 = *(const float4*)&op[0];
                float4 o1 = *(const float4*)&op[4];
                o0.x += acc[i][0]; o0.y += acc[i][1];
                o0.z += acc[i][2]; o0.w += acc[i][3];
                o1.x += acc[i][4]; o1.y += acc[i][5];
                o1.z += acc[i][6]; o1.w += acc[i][7];
                *(float4*)&op[0] = o0;
                *(float4*)&op[4] = o1;
            }
        }
    }
}

// row L2 norm of h rows (256 wide), 1 wave per row
__global__ __launch_bounds__(64) void rownorm_kernel(
    const float* __restrict__ h, float* __restrict__ nrm)
{
    const size_t row = blockIdx.x;
    const int t = threadIdx.x;
    float4 v = *(const float4*)&h[row * 256 + t * 4];
    float s = v.x * v.x + v.y * v.y + v.z * v.z + v.w * v.w;
    #pragma unroll
    for (int m = 1; m < 64; m <<= 1) s += __shfl_xor(s, m);
    if (t == 0) nrm[row] = sqrtf(s);
}

// softmax over N=360 per batch, 1 wave per batch
__global__ __launch_bounds__(64) void softmax_n_kernel(
    const float* __restrict__ nrm, float* __restrict__ attn)
{
    const int b = blockIdx.x;
    const int t = threadIdx.x;
    float v[6];
    float mx = -1e30f;
    #pragma unroll
    for (int i = 0; i < 6; ++i) {
        int m = t + i * 64;
        v[i] = (m < N_) ? nrm[b * N_ + m] : -1e30f;
        mx = fmaxf(mx, v[i]);
    }
    #pragma unroll
    for (int m = 1; m < 64; m <<= 1) mx = fmaxf(mx, __shfl_xor(mx, m));
    float s = 0.f;
    #pragma unroll
    for (int i = 0; i < 6; ++i) {
        int m = t + i * 64;
        float p = (m < N_) ? __expf(v[i] - mx) : 0.f;
        v[i] = p;
        s += p;
    }
    #pragma unroll
    for (int m = 1; m < 64; m <<= 1) s += __shfl_xor(s, m);
    const float inv = 1.f / s;
    #pragma unroll
    for (int i = 0; i < 6; ++i) {
        int m = t + i * 64;
        if (m < N_) attn[b * N_ + m] = v[i] * inv;
    }
}

// ge[b,c] = sum_n attn[b,n] * h[b,n,c]
__global__ __launch_bounds__(256) void ge_kernel(
    const float* __restrict__ attn, const float* __restrict__ h, float* __restrict__ ge)
{
    __shared__ float a[N_];
    const int b = blockIdx.x;
    const int t = threadIdx.x;
    for (int m = t; m < N_; m += 256) a[m] = attn[b * N_ + m];
    __syncthreads();
    float acc = 0.f;
    const float* hp = h + (size_t)b * N_ * 256 + t;
    for (int m = 0; m < N_; ++m) acc += a[m] * hp[(size_t)m * 256];
    ge[b * 256 + t] = acc;
}

// Y[b,c] = (gelu?)(X[b,:] @ W[:,c] + bias[c])
__global__ __launch_bounds__(256) void mlp_kernel(
    const float* __restrict__ X, const float* __restrict__ W,
    const float* __restrict__ bias, float* __restrict__ Y, int applyGelu)
{
    __shared__ float xs[256];
    const int b = blockIdx.x;
    const int t = threadIdx.x;
    xs[t] = X[b * 256 + t];
    __syncthreads();
    float acc = bias[t];
    for (int k = 0; k < 256; ++k) acc += xs[k] * W[k * 256 + t];
    if (applyGelu) acc = gelu_f(acc);
    Y[b * 256 + t] = acc;
}

// ---------------------------------------------------------------------------

extern "C" void kernel_launch(void* const* d_in, const int* in_sizes, int n_in,
                              void* d_out, int out_size, void* d_ws, size_t ws_size,
                              hipStream_t stream) {
    const float* mind  = (const float*)d_in[0];
    const float* roi   = (const float*)d_in[1];
    const float* Wnp   = (const float*)d_in[3];
    const float* bnp   = (const float*)d_in[4];
    const float* Wrf   = (const float*)d_in[5];
    const float* brf   = (const float*)d_in[6];
    const float* ln_g  = (const float*)d_in[7];
    const float* ln_b  = (const float*)d_in[8];
    const float* gatW0 = (const float*)d_in[13];
    const float* gata0 = (const float*)d_in[14];
    const float* gatW1 = (const float*)d_in[15];
    const float* gata1 = (const float*)d_in[16];
    const float* gatW2 = (const float*)d_in[17];
    const float* gata2 = (const float*)d_in[18];
    const float* projW = (const float*)d_in[19];
    const float* projb = (const float*)d_in[20];
    const float* Wr1   = (const float*)d_in[21];
    const float* br1   = (const float*)d_in[22];
    const float* Wr2   = (const float*)d_in[23];
    const float* br2   = (const float*)d_in[24];

    const size_t SZ = (size_t)ROWS_ * D_;       // 5,898,240 floats
    float* ws = (float*)d_ws;
    float* s0 = ws;                  // h2
    float* s1 = ws + SZ;             // nf -> zbuf[0]
    float* s2 = ws + 2 * SZ;         // ht0/ht1 -> zbuf[1]
    float* s3 = ws + 3 * SZ;         // h1 -> zbuf[2]
    float* s4 = ws + 4 * SZ;         // zbuf[3]
    float* tail  = ws + 5 * SZ;
    float* ei_b  = tail;                         // 23040*8
    float* ej_b  = ei_b + (size_t)ROWS_ * H_;
    float* Wcomb = ej_b + (size_t)ROWS_ * H_;    // 360*256
    float* bcomb = Wcomb + 360 * 256;            // 256
    float* Gbuf  = bcomb + 256;                  // 8*256*256
    float* uvec  = Gbuf + 8 * 256 * 256;         // 8*256
    float* vvec  = uvec + 8 * 256;
    float* norms = vvec + 8 * 256;               // 23040
    float* ge0   = norms + ROWS_;
    float* ge1   = ge0 + B_ * D_;

    const size_t need = (size_t)(ge1 + B_ * D_ - ws) * sizeof(float);
    if (ws_size < need) return;

    float* out    = (float*)d_out;
    float* out_ge = out;
    float* out_h  = out + (size_t)B_ * D_;
    float* out_at = out_h + (size_t)ROWS_ * D_;

    const dim3 blk(256);

    // --- node feature fusion ---
    gemm_tiled<<<dim3(4, 3), blk, 0, stream>>>(
        Wnp, Wrf, 256, 256, 256,
        nullptr, nullptr, 0, 0, 0,
        nullptr, Wcomb, 360, 256, 256, 0, 0, 0);
    biascomb_kernel<<<1, 256, 0, stream>>>(bnp, Wrf, brf, bcomb);
    gemm_tiled<<<dim3(4, 180), blk, 0, stream>>>(
        mind, Wcomb, 360, 360, 256,
        roi, Wrf + 256 * 256, 256, 256, 256,
        bcomb, s1, ROWS_, 256, 256, 0, 0, 0);          // nf -> s1
    ln_gelu_kernel<<<ROWS_, 64, 0, stream>>>(s1, ln_g, ln_b);

    // --- GAT layer 0 (dh=32) ---
    gemm_tiled<<<dim3(4, 180), blk, 0, stream>>>(
        s1, gatW0, 256, 256, 256,
        nullptr, nullptr, 0, 0, 0,
        nullptr, s2, ROWS_, 256, 256, 0, 0, 0);        // ht0 -> s2
    eiej_kernel<32><<<ROWS_, 64, 0, stream>>>(s2, gata0, ei_b, ej_b);
    gat01_aggC<<<dim3(H_, B_), blk, 0, stream>>>(s2, ei_b, ej_b, s3);  // h1 -> s3

    // --- GAT layer 1 (dh=32) ---
    gemm_tiled<<<dim3(4, 180), blk, 0, stream>>>(
        s3, gatW1, 256, 256, 256,
        nullptr, nullptr, 0, 0, 0,
        nullptr, s2, ROWS_, 256, 256, 0, 0, 0);        // ht1 -> s2
    eiej_kernel<32><<<ROWS_, 64, 0, stream>>>(s2, gata1, ei_b, ej_b);
    gat01_aggC<<<dim3(H_, B_), blk, 0, stream>>>(s2, ei_b, ej_b, s0);  // h2 -> s0

    // --- GAT layer 2 (collapsed): G_h = gatW2_h @ projW_h; out = sum_h a_h@(h2@G_h)
    gemm_tiled<<<dim3(4, 2, 8), blk, 0, stream>>>(
        gatW2, projW, 256, 2048, 256,
        nullptr, nullptr, 0, 0, 0,
        nullptr, Gbuf, 256, 256, 256,
        256, (size_t)256 * 256, (size_t)256 * 256);
    uv_kernel<<<8, 256, 0, stream>>>(gatW2, gata2, uvec, vvec);
    eiej2_kernel<<<ROWS_, 64, 0, stream>>>(s0, uvec, vvec, ei_b, ej_b);

    // heads 0-3: Z_0..3 -> s1..s4 (z-batched), then fused 4-head aggregate
    gemm_tiled<<<dim3(4, 180, 4), blk, 0, stream>>>(
        s0, Gbuf, 256, 256, 256,
        nullptr, nullptr, 0, 0, 0,
        nullptr, s1, ROWS_, 256, 256,
        0, (size_t)256 * 256, SZ);
    gat2_aggC4<<<dim3(8, B_), blk, 0, stream>>>(
        s1, SZ, ei_b, ej_b, projb, out_h, 0, 1);
    // heads 4-7
    gemm_tiled<<<dim3(4, 180, 4), blk, 0, stream>>>(
        s0, Gbuf + (size_t)4 * 256 * 256, 256, 256, 256,
        nullptr, nullptr, 0, 0, 0,
        nullptr, s1, ROWS_, 256, 256,
        0, (size_t)256 * 256, SZ);
    gat2_aggC4<<<dim3(8, B_), blk, 0, stream>>>(
        s1, SZ, ei_b, ej_b, projb, out_h, 4, 0);

    // --- attention readout ---
    rownorm_kernel<<<ROWS_, 64, 0, stream>>>(out_h, norms);
    softmax_n_kernel<<<B_, 64, 0, stream>>>(norms, out_at);
    ge_kernel<<<B_, 256, 0, stream>>>(out_at, out_h, ge0);
    mlp_kernel<<<B_, 256, 0, stream>>>(ge0, Wr1, br1, ge1, 1);
    mlp_kernel<<<B_, 256, 0, stream>>>(ge1, Wr2, br2, out_ge, 0);
}

// Round 10
// 2053.924 us; speedup vs baseline: 1.2721x; 1.2721x over previous
//
#include <hip/hip_runtime.h>
#include <hip/hip_bf16.h>
#include <math.h>

// ---------------------------------------------------------------------------
// PriorEnhancedMindEncoder forward, fp32.
// Shapes: B=64, N=360, DH=256, H=8. dh(GAT0/1)=32, dh(GAT2)=256.
//
// Dead-code: adj_norm strictly positive -> GAT mask all-true -> group_prior/
// Wp1/Wp2 branch skipped.
// Fusion 1: nf = mind@(Wnp@Wrf_top) + roi@Wrf_bot + (bnp@Wrf_top+brf), LN+GELU.
// Fusion 2: GAT2 collapse: out = sum_h alpha_h @ (h2 @ G_h), G_h = gatW2_h@projW_h.
// R3: gemm 128x64 tile, 8x4 microtile, K-step 32, dbuf LDS.
// R9 post-mortem: col-tiled agg fixed fetch (390->61MB) but broke compute
//     (VALU 36%, 8.3M LDS conflicts, 96 barrier pairs) -> 599us. R10: revert
//     to R8 row-tiled structure (0 conflicts, VALU 51%) + fix memory via
//     XCD co-location: blkid = ntile*64 + b puts all 12 same-b blocks on
//     XCD b%8 (xcd = blkid%8), co-resident (768 = 3/CU) -> Z rows hit L2.
//     Plus single-exp-pass (rsum folded into multiply loop, per-head
//     normalization folded into cross-head register accumulator).
// ---------------------------------------------------------------------------

#define B_ 64
#define N_ 360
#define D_ 256
#define H_ 8
#define ROWS_ (B_ * N_)   // 23040
#define CHUNK01 30
#define SCPAD 964         // per-head score block stride (30*32 + 4), floats

__device__ __forceinline__ float gelu_f(float x) {
    return 0.5f * x * (1.f + erff(x * 0.70710678118654752440f));
}

// ---------------------------------------------------------------------------
// Tiled fp32 GEMM: C[M,N] = A1[M,K1]@B1[K1,N] (+ A2[M,K2]@B2[K2,N]) + bias
// 128x64 tile, 256 threads, 8x4 microtile, K-step 32, double-buffered LDS.
// z-batch: pass-0 A/B and C shifted by z*sA / z*sB / z*sC elements.
// ---------------------------------------------------------------------------
__global__ __launch_bounds__(256) void gemm_tiled(
    const float* __restrict__ A1, const float* __restrict__ B1, int K1, int lda1, int ldb1,
    const float* __restrict__ A2, const float* __restrict__ B2, int K2, int lda2, int ldb2,
    const float* __restrict__ bias, float* __restrict__ C, int M, int N, int ldc,
    size_t sA, size_t sB, size_t sC)
{
    __shared__ float As[2][32][132];
    __shared__ float Bs[2][32][64];
    const int tid = threadIdx.x;
    const int z = blockIdx.z;
    const int bm = blockIdx.y * 128;
    const int bn = blockIdx.x * 64;
    const int tr = (tid >> 4) * 8;
    const int tc = (tid & 15) * 4;
    const int lar = tid >> 3;
    const int lak = (tid & 7) * 4;
    const int lbk = tid >> 4;
    const int lbc = (tid & 15) * 4;

    float acc[8][4] = {};
    float4 rA[4], rB[2];

    for (int pass = 0; pass < 2; ++pass) {
        const float* Ab = pass ? A2 : A1;
        const float* Bb = pass ? B2 : B1;
        if (Ab == nullptr) continue;
        const float* A  = Ab + (pass ? (size_t)0 : (size_t)z * sA);
        const float* Bm = Bb + (pass ? (size_t)0 : (size_t)z * sB);
        const int K   = pass ? K2 : K1;
        const int lda = pass ? lda2 : lda1;
        const int ldb = pass ? ldb2 : ldb1;
        const int S = (K + 31) >> 5;

        auto loadA = [&](int s) {
            const int k0 = s << 5;
            #pragma unroll
            for (int j = 0; j < 4; ++j) {
                const int gr = bm + lar + j * 32;
                const int gk = k0 + lak;
                float4 v; v.x = v.y = v.z = v.w = 0.f;
                if (gr < M) {
                    if (gk + 3 < K) {
                        v = *(const float4*)&A[(size_t)gr * lda + gk];
                    } else {
                        float t0 = 0.f, t1 = 0.f, t2 = 0.f, t3 = 0.f;
                        if (gk + 0 < K) t0 = A[(size_t)gr * lda + gk + 0];
                        if (gk + 1 < K) t1 = A[(size_t)gr * lda + gk + 1];
                        if (gk + 2 < K) t2 = A[(size_t)gr * lda + gk + 2];
                        if (gk + 3 < K) t3 = A[(size_t)gr * lda + gk + 3];
                        v.x = t0; v.y = t1; v.z = t2; v.w = t3;
                    }
                }
                rA[j] = v;
            }
        };
        auto loadB = [&](int s) {
            const int k0 = s << 5;
            #pragma unroll
            for (int j = 0; j < 2; ++j) {
                const int gk = k0 + lbk + j * 16;
                float4 v; v.x = v.y = v.z = v.w = 0.f;
                if (gk < K) v = *(const float4*)&Bm[(size_t)gk * ldb + bn + lbc];
                rB[j] = v;
            }
        };
        auto storeA = [&](int buf) {
            #pragma unroll
            for (int j = 0; j < 4; ++j) {
                const int row = lar + j * 32;
                As[buf][lak + 0][row] = rA[j].x;
                As[buf][lak + 1][row] = rA[j].y;
                As[buf][lak + 2][row] = rA[j].z;
                As[buf][lak + 3][row] = rA[j].w;
            }
        };
        auto storeB = [&](int buf) {
            #pragma unroll
            for (int j = 0; j < 2; ++j)
                *(float4*)&Bs[buf][lbk + j * 16][lbc] = rB[j];
        };

        loadA(0); loadB(0);
        storeA(0); storeB(0);
        __syncthreads();
        for (int s = 0; s < S; ++s) {
            const int cur = s & 1;
            if (s + 1 < S) { loadA(s + 1); loadB(s + 1); }
            #pragma unroll
            for (int k = 0; k < 32; ++k) {
                const float4 a0 = *(const float4*)&As[cur][k][tr];
                const float4 a1 = *(const float4*)&As[cur][k][tr + 4];
                const float4 bv = *(const float4*)&Bs[cur][k][tc];
                const float av[8] = {a0.x, a0.y, a0.z, a0.w, a1.x, a1.y, a1.z, a1.w};
                const float bb[4] = {bv.x, bv.y, bv.z, bv.w};
                #pragma unroll
                for (int i = 0; i < 8; ++i)
                    #pragma unroll
                    for (int j = 0; j < 4; ++j)
                        acc[i][j] += av[i] * bb[j];
            }
            if (s + 1 < S) { storeA(cur ^ 1); storeB(cur ^ 1); }
            __syncthreads();
        }
    }

    float4 bz; bz.x = bz.y = bz.z = bz.w = 0.f;
    if (bias) bz = *(const float4*)&bias[bn + tc];
    float* Cz = C + (size_t)z * sC;
    #pragma unroll
    for (int i = 0; i < 8; ++i) {
        const int r = bm + tr + i;
        if (r < M) {
            float4 o;
            o.x = acc[i][0] + bz.x;
            o.y = acc[i][1] + bz.y;
            o.z = acc[i][2] + bz.z;
            o.w = acc[i][3] + bz.w;
            *(float4*)&Cz[(size_t)r * ldc + bn + tc] = o;
        }
    }
}

// bias_comb[c] = brf[c] + sum_k bnp[k] * Wrf[k, c]
__global__ __launch_bounds__(256) void biascomb_kernel(
    const float* __restrict__ bnp, const float* __restrict__ Wrf,
    const float* __restrict__ brf, float* __restrict__ bcomb)
{
    int c = threadIdx.x;
    float acc = brf[c];
    for (int k = 0; k < 256; ++k) acc += bnp[k] * Wrf[k * 256 + c];
    bcomb[c] = acc;
}

// u[h][i] = sum_j gatW2[i, h*256+j] * a2[h, j]; v[h][i] with a2[h, 256+j]
__global__ __launch_bounds__(256) void uv_kernel(
    const float* __restrict__ gatW2, const float* __restrict__ a2,
    float* __restrict__ u, float* __restrict__ v)
{
    const int h = blockIdx.x;
    const int i = threadIdx.x;
    const float* wrow = gatW2 + (size_t)i * 2048 + h * 256;
    const float* ai = a2 + h * 512;
    float su = 0.f, sv = 0.f;
    for (int j = 0; j < 256; ++j) {
        float w = wrow[j];
        su += w * ai[j];
        sv += w * ai[256 + j];
    }
    u[h * 256 + i] = su;
    v[h * 256 + i] = sv;
}

// LayerNorm(eps=1e-5) + exact GELU, in-place on rows of 256. 1 wave per row.
__global__ __launch_bounds__(64) void ln_gelu_kernel(
    float* __restrict__ x, const float* __restrict__ g, const float* __restrict__ b)
{
    const size_t row = blockIdx.x;
    const int t = threadIdx.x;
    float4 v = *(const float4*)&x[row * 256 + t * 4];
    float s = v.x + v.y + v.z + v.w;
    #pragma unroll
    for (int m = 1; m < 64; m <<= 1) s += __shfl_xor(s, m);
    float mean = s * (1.f / 256.f);
    float dx = v.x - mean, dy = v.y - mean, dz = v.z - mean, dw = v.w - mean;
    float q = dx * dx + dy * dy + dz * dz + dw * dw;
    #pragma unroll
    for (int m = 1; m < 64; m <<= 1) q += __shfl_xor(q, m);
    float rstd = 1.f / sqrtf(q * (1.f / 256.f) + 1e-5f);
    float4 gg = *(const float4*)&g[t * 4];
    float4 bb = *(const float4*)&b[t * 4];
    float4 r;
    r.x = gelu_f(dx * rstd * gg.x + bb.x);
    r.y = gelu_f(dy * rstd * gg.y + bb.y);
    r.z = gelu_f(dz * rstd * gg.z + bb.z);
    r.w = gelu_f(dw * rstd * gg.w + bb.w);
    *(float4*)&x[row * 256 + t * 4] = r;
}

// ei/ej for GAT0/1: per row: ei[h] = ht[row,h,:dh] . a[h,:dh]
template <int DH>
__global__ __launch_bounds__(64) void eiej_kernel(
    const float* __restrict__ ht, const float* __restrict__ a,
    float* __restrict__ ei, float* __restrict__ ej)
{
    const size_t row = blockIdx.x;
    const int t = threadIdx.x;
    constexpr int E = (H_ * DH) / 64;
    const int h = t >> 3;
    const int d0 = (t & 7) * E;
    const float* hp = ht + row * (H_ * DH) + h * DH + d0;
    const float* ap = a + h * 2 * DH + d0;
    float se = 0.f, sj = 0.f;
    #pragma unroll
    for (int i = 0; i < E; i += 4) {
        float4 x = *(const float4*)&hp[i];
        float4 u = *(const float4*)&ap[i];
        float4 w = *(const float4*)&ap[DH + i];
        se += x.x * u.x + x.y * u.y + x.z * u.z + x.w * u.w;
        sj += x.x * w.x + x.y * w.y + x.z * w.z + x.w * w.w;
    }
    se += __shfl_xor(se, 1); sj += __shfl_xor(sj, 1);
    se += __shfl_xor(se, 2); sj += __shfl_xor(sj, 2);
    se += __shfl_xor(se, 4); sj += __shfl_xor(sj, 4);
    if ((t & 7) == 0) {
        ei[row * H_ + h] = se;
        ej[row * H_ + h] = sj;
    }
}

// ei2/ej2 for GAT2: ei2[row,h] = h2[row,:] . u[h,:], ej2 with v.
__global__ __launch_bounds__(64) void eiej2_kernel(
    const float* __restrict__ h2, const float* __restrict__ u,
    const float* __restrict__ v, float* __restrict__ ei, float* __restrict__ ej)
{
    const size_t row = blockIdx.x;
    const int t = threadIdx.x;
    const int h = t >> 3;
    const int d0 = (t & 7) * 32;
    const float* hp = h2 + row * 256 + d0;
    const float* up = u + h * 256 + d0;
    const float* vp = v + h * 256 + d0;
    float se = 0.f, sj = 0.f;
    #pragma unroll
    for (int i = 0; i < 32; i += 4) {
        float4 x = *(const float4*)&hp[i];
        float4 uu = *(const float4*)&up[i];
        float4 vv = *(const float4*)&vp[i];
        se += x.x * uu.x + x.y * uu.y + x.z * uu.z + x.w * uu.w;
        sj += x.x * vv.x + x.y * vv.y + x.z * vv.z + x.w * vv.w;
    }
    se += __shfl_xor(se, 1); sj += __shfl_xor(sj, 1);
    se += __shfl_xor(se, 2); sj += __shfl_xor(sj, 2);
    se += __shfl_xor(se, 4); sj += __shfl_xor(sj, 4);
    if ((t & 7) == 0) {
        ei[row * H_ + h] = se;
        ej[row * H_ + h] = sj;
    }
}

// ---------------------------------------------------------------------------
// GAT0/1 aggregation, ALL 8 heads per block. 1-D grid 768: blkid = ntile*64
// + b -> XCD = blkid%8 = b%8: all 12 same-b blocks co-located so ht[b] rows
// hit that XCD's L2. Output tile 32 rows x 256 cols. Scores chunked 30-m in
// scT[8][30][32]+pad; V = contiguous 1KB ht rows; unnormalized p + epilogue.
// ---------------------------------------------------------------------------
__global__ __launch_bounds__(256) void gat01_agg(
    const float* __restrict__ ht, const float* __restrict__ ei,
    const float* __restrict__ ej, float* __restrict__ out)
{
    __shared__ float scT[8 * SCPAD];     // 30848 B
    __shared__ float ejs[8][N_];         // 11520 B  [h][m]
    __shared__ float eis[8][32];
    __shared__ float rinv_s[8][32];
    __shared__ float maxej_s[8];
    const int tid = threadIdx.x;
    const int b  = blockIdx.x & 63;
    const int n0 = (blockIdx.x >> 6) * 32;
    const int nrows = min(32, N_ - n0);

    for (int idx = tid; idx < N_ * H_; idx += 256) {
        const int m = idx >> 3, h = idx & 7;
        ejs[h][m] = ej[(size_t)(b * N_ + m) * H_ + h];
    }
    const int ph = tid >> 5, pr = tid & 31;    // score-role: head, row
    eis[ph][pr] = (pr < nrows) ? ei[(size_t)(b * N_ + n0 + pr) * H_ + ph] : 0.f;
    __syncthreads();

    {   // per-head max over ej (32 threads/head)
        float mx = -1e30f;
        for (int m = pr; m < N_; m += 32) mx = fmaxf(mx, ejs[ph][m]);
        mx = fmaxf(mx, __shfl_xor(mx, 1));
        mx = fmaxf(mx, __shfl_xor(mx, 2));
        mx = fmaxf(mx, __shfl_xor(mx, 4));
        mx = fmaxf(mx, __shfl_xor(mx, 8));
        mx = fmaxf(mx, __shfl_xor(mx, 16));
        if (pr == 0) maxej_s[ph] = mx;
    }
    __syncthreads();

    const float ei_r = eis[ph][pr];
    float mrow = ei_r + maxej_s[ph];
    mrow = mrow > 0.f ? mrow : 0.2f * mrow;    // lrelu monotonic -> row max
    float rsum = 0.f;

    const int rg = tid >> 5, cg = tid & 31;    // multiply-role
    const int vh = cg >> 2;                    // head owning cols cg*8..+7
    const float* Vp = ht + (size_t)b * N_ * D_ + cg * 8;
    float acc[4][8] = {};

    for (int c0 = 0; c0 < N_; c0 += CHUNK01) {
        // scores for m in [c0, c0+30)
        float* sp = scT + ph * SCPAD + pr;
        #pragma unroll 6
        for (int mm = 0; mm < CHUNK01; ++mm) {
            float e = ei_r + ejs[ph][c0 + mm];
            e = e > 0.f ? e : 0.2f * e;
            float p = __expf(e - mrow);
            sp[mm * 32] = p;
            rsum += p;
        }
        __syncthreads();
        // multiply
        const float* st = scT + vh * SCPAD + rg * 4;
        #pragma unroll 2
        for (int mm = 0; mm < CHUNK01; ++mm) {
            const int m = c0 + mm;
            const float4 a4 = *(const float4*)&st[mm * 32];
            const float4 v0 = *(const float4*)&Vp[(size_t)m * D_];
            const float4 v1 = *(const float4*)&Vp[(size_t)m * D_ + 4];
            const float a[4] = {a4.x, a4.y, a4.z, a4.w};
            const float v[8] = {v0.x, v0.y, v0.z, v0.w, v1.x, v1.y, v1.z, v1.w};
            #pragma unroll
            for (int i = 0; i < 4; ++i)
                #pragma unroll
                for (int j = 0; j < 8; ++j)
                    acc[i][j] += a[i] * v[j];
        }
        __syncthreads();
    }

    rinv_s[ph][pr] = 1.f / rsum;
    __syncthreads();

    #pragma unroll
    for (int i = 0; i < 4; ++i) {
        const int r = rg * 4 + i;
        if (r < nrows) {
            const float ri = rinv_s[vh][r];
            float* op = out + (size_t)(b * N_ + n0 + r) * D_ + cg * 8;
            float4 o0, o1;
            o0.x = acc[i][0] * ri; o0.y = acc[i][1] * ri;
            o0.z = acc[i][2] * ri; o0.w = acc[i][3] * ri;
            o1.x = acc[i][4] * ri; o1.y = acc[i][5] * ri;
            o1.z = acc[i][6] * ri; o1.w = acc[i][7] * ri;
            *(float4*)&op[0] = o0;
            *(float4*)&op[4] = o1;
        }
    }
}

// ---------------------------------------------------------------------------
// GAT2 aggregation, 4 heads/dispatch, register accumulator across heads.
// 1-D grid 768: blkid = ntile*64 + b -> all 12 same-b blocks on XCD b%8 so
// Z_h[b] rows hit L2 (R8 row-robin cost 4x HBM re-fetch). Single exp pass:
// unnormalized p in scT; rsum accumulated in multiply loop; per-head
// normalization folded into cross-head acc.  first: out = acc+projb else +=.
// ---------------------------------------------------------------------------
__global__ __launch_bounds__(256) void gat2_agg4(
    const float* __restrict__ Zbase, size_t zstride,
    const float* __restrict__ ei, const float* __restrict__ ej,
    const float* __restrict__ projb, float* __restrict__ out,
    int hbase, int first)
{
    __shared__ float scT[N_][32];     // 46080 B
    __shared__ float ejs[N_];
    __shared__ float eis[32];
    __shared__ float red4[4];
    const int tid = threadIdx.x;
    const int b  = blockIdx.x & 63;
    const int n0 = (blockIdx.x >> 6) * 32;
    const int nrows = min(32, N_ - n0);
    const int rg = tid >> 5, cg = tid & 31;
    const int sr = tid & 31, sub = tid >> 5;   // score-role
    float acc[4][8] = {};

    for (int hh = 0; hh < 4; ++hh) {
        const int h = hbase + hh;
        for (int m = tid; m < N_; m += 256) ejs[m] = ej[(size_t)(b * N_ + m) * H_ + h];
        if (tid < 32) eis[tid] = (tid < nrows) ? ei[(size_t)(b * N_ + n0 + tid) * H_ + h] : 0.f;
        __syncthreads();

        float mx = -1e30f;
        for (int m = tid; m < N_; m += 256) mx = fmaxf(mx, ejs[m]);
        #pragma unroll
        for (int s = 1; s < 64; s <<= 1) mx = fmaxf(mx, __shfl_xor(mx, s));
        if ((tid & 63) == 0) red4[tid >> 6] = mx;
        __syncthreads();
        const float maxej = fmaxf(fmaxf(red4[0], red4[1]), fmaxf(red4[2], red4[3]));

        // single pass: unnormalized p into scT
        const float ei_r = eis[sr];
        float mrow = ei_r + maxej;
        mrow = mrow > 0.f ? mrow : 0.2f * mrow;
        for (int m = sub; m < N_; m += 8) {
            float e = ei_r + ejs[m];
            e = e > 0.f ? e : 0.2f * e;
            scT[m][sr] = __expf(e - mrow);
        }
        __syncthreads();

        // multiply: acc_h += p_h @ Z_h; rsum rides along (4 adds / 32 FMA)
        const float* Vp = Zbase + (size_t)hh * zstride + (size_t)b * N_ * D_ + cg * 8;
        float acc_h[4][8] = {};
        float rsum[4] = {};
        #pragma unroll 2
        for (int m = 0; m < N_; ++m) {
            const float4 a4 = *(const float4*)&scT[m][rg * 4];
            const float4 v0 = *(const float4*)&Vp[(size_t)m * D_];
            const float4 v1 = *(const float4*)&Vp[(size_t)m * D_ + 4];
            const float a[4] = {a4.x, a4.y, a4.z, a4.w};
            const float v[8] = {v0.x, v0.y, v0.z, v0.w, v1.x, v1.y, v1.z, v1.w};
            #pragma unroll
            for (int i = 0; i < 4; ++i) {
                rsum[i] += a[i];
                #pragma unroll
                for (int j = 0; j < 8; ++j)
                    acc_h[i][j] += a[i] * v[j];
            }
        }
        #pragma unroll
        for (int i = 0; i < 4; ++i) {
            const float ri = 1.f / rsum[i];
            #pragma unroll
            for (int j = 0; j < 8; ++j)
                acc[i][j] += acc_h[i][j] * ri;
        }
        __syncthreads();   // done with scT/ejs/eis before next head reload
    }

    #pragma unroll
    for (int i = 0; i < 4; ++i) {
        const int r = rg * 4 + i;
        if (r < nrows) {
            float* op = out + (size_t)(b * N_ + n0 + r) * D_ + cg * 8;
            if (first) {
                const float4 p0 = *(const float4*)&projb[cg * 8];
                const float4 p1 = *(const float4*)&projb[cg * 8 + 4];
                float4 o0, o1;
                o0.x = acc[i][0] + p0.x; o0.y = acc[i][1] + p0.y;
                o0.z = acc[i][2] + p0.z; o0.w = acc[i][3] + p0.w;
                o1.x = acc[i][4] + p1.x; o1.y = acc[i][5] + p1.y;
                o1.z = acc[i][6] + p1.z; o1.w = acc[i][7] + p1.w;
                *(float4*)&op[0] = o0;
                *(float4*)&op[4] = o1;
            } else {
                float4 o0 = *(const float4*)&op[0];
                float4 o1 = *(const float4*)&op[4];
                o0.x += acc[i][0]; o0.y += acc[i][1];
                o0.z += acc[i][2]; o0.w += acc[i][3];
                o1.x += acc[i][4]; o1.y += acc[i][5];
                o1.z += acc[i][6]; o1.w += acc[i][7];
                *(float4*)&op[0] = o0;
                *(float4*)&op[4] = o1;
            }
        }
    }
}

// row L2 norm of h rows (256 wide), 1 wave per row
__global__ __launch_bounds__(64) void rownorm_kernel(
    const float* __restrict__ h, float* __restrict__ nrm)
{
    const size_t row = blockIdx.x;
    const int t = threadIdx.x;
    float4 v = *(const float4*)&h[row * 256 + t * 4];
    float s = v.x * v.x + v.y * v.y + v.z * v.z + v.w * v.w;
    #pragma unroll
    for (int m = 1; m < 64; m <<= 1) s += __shfl_xor(s, m);
    if (t == 0) nrm[row] = sqrtf(s);
}

// softmax over N=360 per batch, 1 wave per batch
__global__ __launch_bounds__(64) void softmax_n_kernel(
    const float* __restrict__ nrm, float* __restrict__ attn)
{
    const int b = blockIdx.x;
    const int t = threadIdx.x;
    float v[6];
    float mx = -1e30f;
    #pragma unroll
    for (int i = 0; i < 6; ++i) {
        int m = t + i * 64;
        v[i] = (m < N_) ? nrm[b * N_ + m] : -1e30f;
        mx = fmaxf(mx, v[i]);
    }
    #pragma unroll
    for (int m = 1; m < 64; m <<= 1) mx = fmaxf(mx, __shfl_xor(mx, m));
    float s = 0.f;
    #pragma unroll
    for (int i = 0; i < 6; ++i) {
        int m = t + i * 64;
        float p = (m < N_) ? __expf(v[i] - mx) : 0.f;
        v[i] = p;
        s += p;
    }
    #pragma unroll
    for (int m = 1; m < 64; m <<= 1) s += __shfl_xor(s, m);
    const float inv = 1.f / s;
    #pragma unroll
    for (int i = 0; i < 6; ++i) {
        int m = t + i * 64;
        if (m < N_) attn[b * N_ + m] = v[i] * inv;
    }
}

// ge[b,c] = sum_n attn[b,n] * h[b,n,c]
__global__ __launch_bounds__(256) void ge_kernel(
    const float* __restrict__ attn, const float* __restrict__ h, float* __restrict__ ge)
{
    __shared__ float a[N_];
    const int b = blockIdx.x;
    const int t = threadIdx.x;
    for (int m = t; m < N_; m += 256) a[m] = attn[b * N_ + m];
    __syncthreads();
    float acc = 0.f;
    const float* hp = h + (size_t)b * N_ * 256 + t;
    for (int m = 0; m < N_; ++m) acc += a[m] * hp[(size_t)m * 256];
    ge[b * 256 + t] = acc;
}

// Y[b,c] = (gelu?)(X[b,:] @ W[:,c] + bias[c])
__global__ __launch_bounds__(256) void mlp_kernel(
    const float* __restrict__ X, const float* __restrict__ W,
    const float* __restrict__ bias, float* __restrict__ Y, int applyGelu)
{
    __shared__ float xs[256];
    const int b = blockIdx.x;
    const int t = threadIdx.x;
    xs[t] = X[b * 256 + t];
    __syncthreads();
    float acc = bias[t];
    for (int k = 0; k < 256; ++k) acc += xs[k] * W[k * 256 + t];
    if (applyGelu) acc = gelu_f(acc);
    Y[b * 256 + t] = acc;
}

// ---------------------------------------------------------------------------

extern "C" void kernel_launch(void* const* d_in, const int* in_sizes, int n_in,
                              void* d_out, int out_size, void* d_ws, size_t ws_size,
                              hipStream_t stream) {
    const float* mind  = (const float*)d_in[0];
    const float* roi   = (const float*)d_in[1];
    const float* Wnp   = (const float*)d_in[3];
    const float* bnp   = (const float*)d_in[4];
    const float* Wrf   = (const float*)d_in[5];
    const float* brf   = (const float*)d_in[6];
    const float* ln_g  = (const float*)d_in[7];
    const float* ln_b  = (const float*)d_in[8];
    const float* gatW0 = (const float*)d_in[13];
    const float* gata0 = (const float*)d_in[14];
    const float* gatW1 = (const float*)d_in[15];
    const float* gata1 = (const float*)d_in[16];
    const float* gatW2 = (const float*)d_in[17];
    const float* gata2 = (const float*)d_in[18];
    const float* projW = (const float*)d_in[19];
    const float* projb = (const float*)d_in[20];
    const float* Wr1   = (const float*)d_in[21];
    const float* br1   = (const float*)d_in[22];
    const float* Wr2   = (const float*)d_in[23];
    const float* br2   = (const float*)d_in[24];

    const size_t SZ = (size_t)ROWS_ * D_;       // 5,898,240 floats
    float* ws = (float*)d_ws;
    float* s0 = ws;                  // h2
    float* s1 = ws + SZ;             // nf -> zbuf[0]
    float* s2 = ws + 2 * SZ;         // ht0/ht1 -> zbuf[1]
    float* s3 = ws + 3 * SZ;         // h1 -> zbuf[2]
    float* s4 = ws + 4 * SZ;         // zbuf[3]
    float* tail  = ws + 5 * SZ;
    float* ei_b  = tail;                         // 23040*8
    float* ej_b  = ei_b + (size_t)ROWS_ * H_;
    float* Wcomb = ej_b + (size_t)ROWS_ * H_;    // 360*256
    float* bcomb = Wcomb + 360 * 256;            // 256
    float* Gbuf  = bcomb + 256;                  // 8*256*256
    float* uvec  = Gbuf + 8 * 256 * 256;         // 8*256
    float* vvec  = uvec + 8 * 256;
    float* norms = vvec + 8 * 256;               // 23040
    float* ge0   = norms + ROWS_;
    float* ge1   = ge0 + B_ * D_;

    const size_t need = (size_t)(ge1 + B_ * D_ - ws) * sizeof(float);
    if (ws_size < need) return;

    float* out    = (float*)d_out;
    float* out_ge = out;
    float* out_h  = out + (size_t)B_ * D_;
    float* out_at = out_h + (size_t)ROWS_ * D_;

    const dim3 blk(256);

    // --- node feature fusion ---
    gemm_tiled<<<dim3(4, 3), blk, 0, stream>>>(
        Wnp, Wrf, 256, 256, 256,
        nullptr, nullptr, 0, 0, 0,
        nullptr, Wcomb, 360, 256, 256, 0, 0, 0);
    biascomb_kernel<<<1, 256, 0, stream>>>(bnp, Wrf, brf, bcomb);
    gemm_tiled<<<dim3(4, 180), blk, 0, stream>>>(
        mind, Wcomb, 360, 360, 256,
        roi, Wrf + 256 * 256, 256, 256, 256,
        bcomb, s1, ROWS_, 256, 256, 0, 0, 0);          // nf -> s1
    ln_gelu_kernel<<<ROWS_, 64, 0, stream>>>(s1, ln_g, ln_b);

    // --- GAT layer 0 (dh=32) ---
    gemm_tiled<<<dim3(4, 180), blk, 0, stream>>>(
        s1, gatW0, 256, 256, 256,
        nullptr, nullptr, 0, 0, 0,
        nullptr, s2, ROWS_, 256, 256, 0, 0, 0);        // ht0 -> s2
    eiej_kernel<32><<<ROWS_, 64, 0, stream>>>(s2, gata0, ei_b, ej_b);
    gat01_agg<<<dim3(12 * B_), blk, 0, stream>>>(s2, ei_b, ej_b, s3);  // h1 -> s3

    // --- GAT layer 1 (dh=32) ---
    gemm_tiled<<<dim3(4, 180), blk, 0, stream>>>(
        s3, gatW1, 256, 256, 256,
        nullptr, nullptr, 0, 0, 0,
        nullptr, s2, ROWS_, 256, 256, 0, 0, 0);        // ht1 -> s2
    eiej_kernel<32><<<ROWS_, 64, 0, stream>>>(s2, gata1, ei_b, ej_b);
    gat01_agg<<<dim3(12 * B_), blk, 0, stream>>>(s2, ei_b, ej_b, s0);  // h2 -> s0

    // --- GAT layer 2 (collapsed): G_h = gatW2_h @ projW_h; out = sum_h a_h@(h2@G_h)
    gemm_tiled<<<dim3(4, 2, 8), blk, 0, stream>>>(
        gatW2, projW, 256, 2048, 256,
        nullptr, nullptr, 0, 0, 0,
        nullptr, Gbuf, 256, 256, 256,
        256, (size_t)256 * 256, (size_t)256 * 256);
    uv_kernel<<<8, 256, 0, stream>>>(gatW2, gata2, uvec, vvec);
    eiej2_kernel<<<ROWS_, 64, 0, stream>>>(s0, uvec, vvec, ei_b, ej_b);

    // heads 0-3: Z_0..3 -> s1..s4 (z-batched), then fused 4-head aggregate
    gemm_tiled<<<dim3(4, 180, 4), blk, 0, stream>>>(
        s0, Gbuf, 256, 256, 256,
        nullptr, nullptr, 0, 0, 0,
        nullptr, s1, ROWS_, 256, 256,
        0, (size_t)256 * 256, SZ);
    gat2_agg4<<<dim3(12 * B_), blk, 0, stream>>>(
        s1, SZ, ei_b, ej_b, projb, out_h, 0, 1);
    // heads 4-7
    gemm_tiled<<<dim3(4, 180, 4), blk, 0, stream>>>(
        s0, Gbuf + (size_t)4 * 256 * 256, 256, 256, 256,
        nullptr, nullptr, 0, 0, 0,
        nullptr, s1, ROWS_, 256, 256,
        0, (size_t)256 * 256, SZ);
    gat2_agg4<<<dim3(12 * B_), blk, 0, stream>>>(
        s1, SZ, ei_b, ej_b, projb, out_h, 4, 0);

    // --- attention readout ---
    rownorm_kernel<<<ROWS_, 64, 0, stream>>>(out_h, norms);
    softmax_n_kernel<<<B_, 64, 0, stream>>>(norms, out_at);
    ge_kernel<<<B_, 256, 0, stream>>>(out_at, out_h, ge0);
    mlp_kernel<<<B_, 256, 0, stream>>>(ge0, Wr1, br1, ge1, 1);
    mlp_kernel<<<B_, 256, 0, stream>>>(ge1, Wr2, br2, out_ge, 0);
}